// Round 2
// baseline (86.637 us; speedup 1.0000x reference)
//
#include <hip/hip_runtime.h>
#include <math.h>

typedef _Float16 f16x8 __attribute__((ext_vector_type(8)));
typedef _Float16 f16x2 __attribute__((ext_vector_type(2)));
typedef float    f32x4 __attribute__((ext_vector_type(4)));

union F16x8u { f16x8 v; f16x2 h[4]; };

// v_sin_f32 / v_cos_f32 take REVOLUTIONS: sin(2*pi*x) = v_sin(x).
__device__ __forceinline__ float cos1_hw(float x) { return __builtin_amdgcn_cosf(x); }
__device__ __forceinline__ float sin1_hw(float x) { return __builtin_amdgcn_sinf(x); }

// v_cvt_pkrtz_f16_f32 returns a __fp16 vector; bit-cast to our _Float16 pair.
__device__ __forceinline__ f16x2 pkrtz(float a, float b)
{
    return __builtin_bit_cast(f16x2, __builtin_amdgcn_cvt_pkrtz(a, b));
}

// ---------------------------------------------------------------------------
// Complex NUFFT formulation (round 8):
//   ynew(x) = (1/4096) * Re sum_{k,m} F[k,m] e^{2pi i x1 f(k)} e^{2pi i x2 f(m)}
// with F = fft2(y), f(k) = k<32 ? k : k-64  (fftfreq order).
// Coefficient generation is a pure rotation recurrence (4 fma per complex
// coeff, step = (cos 2pi x, sin 2pi x)) -- NO v_rcp, no nearest-grid fixups,
// no W Nyquist term. The old cot-based kernel spent 128 rcps/point on the
// quarter-rate transcendental pipe inside serial chains; that was the 81 us.
// F is precomputed by two tiny DFT passes into d_ws (f16, pre-transposed to
// the exact A-fragment layout), so the main kernel hoists A once from global
// and needs only 4 KB LDS.
// ---------------------------------------------------------------------------

// Pass 1: T[b][n2][k] = sum_n1 y[b,n1,n2] e^{-2pi i k n1/64}   (half2 r,i)
__global__ __launch_bounds__(256)
void dft_pass1(const float* __restrict__ y, f16x2* __restrict__ T)
{
    __shared__ float  YL[4096];
    __shared__ float2 tw[64];
    const int tid = threadIdx.x;
    const int b = blockIdx.x >> 3;
    const int g = blockIdx.x & 7;

    const float4* src = (const float4*)(y + (b << 12));
    float4* dst = (float4*)YL;
#pragma unroll
    for (int i = 0; i < 4; ++i) dst[tid + (i << 8)] = src[tid + (i << 8)];
    if (tid < 64) {
        const float a = (float)tid * (1.0f / 64.0f);
        tw[tid] = make_float2(cos1_hw(a), sin1_hw(a));
    }
    __syncthreads();

    const int k   = tid & 63;          // lane = k  (coalesced output)
    const int wv  = tid >> 6;
    const int n2a = (g << 3) + wv;
    const int n2b = n2a + 4;

    float Tr0 = 0.f, Ti0 = 0.f, Tr1 = 0.f, Ti1 = 0.f;
#pragma unroll 4
    for (int n1 = 0; n1 < 64; ++n1) {
        const float ya = YL[(n1 << 6) + n2a];   // wave-uniform -> broadcast
        const float yb = YL[(n1 << 6) + n2b];
        const float2 w = tw[(k * n1) & 63];     // e^{-i t}: (c, -s)
        Tr0 = fmaf(ya,  w.x, Tr0);
        Ti0 = fmaf(ya, -w.y, Ti0);
        Tr1 = fmaf(yb,  w.x, Tr1);
        Ti1 = fmaf(yb, -w.y, Ti1);
    }
    T[(b << 12) + (n2a << 6) + k] = pkrtz(Tr0, Ti0);
    T[(b << 12) + (n2b << 6) + k] = pkrtz(Tr1, Ti1);
}

// Pass 2: F[k,m] = sum_n2 T[k,n2] e^{-2pi i m n2/64};
// writes Frt[b][m][k], Fit[b][m][k] (transposed, f16) = A-operand layout.
__global__ __launch_bounds__(256)
void dft_pass2(const f16x2* __restrict__ T,
               _Float16* __restrict__ Frt, _Float16* __restrict__ Fit)
{
    __shared__ f16x2  TL[4096];     // [n2][k]
    __shared__ float2 tw[64];
    const int tid = threadIdx.x;
    const int b = blockIdx.x >> 3;
    const int g = blockIdx.x & 7;

    const float4* src = (const float4*)(T + (b << 12));
    float4* dst = (float4*)TL;
#pragma unroll
    for (int i = 0; i < 4; ++i) dst[tid + (i << 8)] = src[tid + (i << 8)];
    if (tid < 64) {
        const float a = (float)tid * (1.0f / 64.0f);
        tw[tid] = make_float2(cos1_hw(a), sin1_hw(a));
    }
    __syncthreads();

    const int k  = tid & 63;           // lane = k  (coalesced output)
    const int wv = tid >> 6;
    const int ma = (g << 3) + wv;
    const int mb = ma + 4;

    float Fr0 = 0.f, Fi0 = 0.f, Fr1 = 0.f, Fi1 = 0.f;
#pragma unroll 4
    for (int n2 = 0; n2 < 64; ++n2) {
        const f16x2 t = TL[(n2 << 6) + k];      // stride-1, 2-way (free)
        const float tr = (float)t[0];
        const float ti = (float)t[1];
        const float2 wa = tw[(ma * n2) & 63];   // wave-uniform
        const float2 wb = tw[(mb * n2) & 63];
        // (tr + i ti)(c - i s) = (tr c + ti s) + i(ti c - tr s)
        Fr0 = fmaf(tr, wa.x, Fr0); Fr0 = fmaf(ti,  wa.y, Fr0);
        Fi0 = fmaf(ti, wa.x, Fi0); Fi0 = fmaf(tr, -wa.y, Fi0);
        Fr1 = fmaf(tr, wb.x, Fr1); Fr1 = fmaf(ti,  wb.y, Fr1);
        Fi1 = fmaf(ti, wb.x, Fi1); Fi1 = fmaf(tr, -wb.y, Fi1);
    }
    const int oa = (b << 12) + (ma << 6) + k;
    const int ob = (b << 12) + (mb << 6) + k;
    Frt[oa] = (_Float16)Fr0;  Fit[oa] = (_Float16)Fi0;
    Frt[ob] = (_Float16)Fr1;  Fit[ob] = (_Float16)Fi1;
}

// Main: per point p, G[p,m] = sum_k F[k,m] E1[p,k]  (4 real MFMAs per
// complex product), then red = Re sum_m G[p,m] E2[p,m] on VALU.
// MFMA layout identical to the proven round-7 kernel:
//   A[row=lrow][k=quad*8+j] (tile nt = m-block, kt = K=32 chunk)
//   B[k=quad*8+j][col=lrow] ; D: col=lrow(p), row=quad*4+reg (m within nt).
__global__ __launch_bounds__(256, 3)
void fourier_interp_cplx(const _Float16* __restrict__ Frt,
                         const _Float16* __restrict__ Fit,
                         const float* __restrict__ xnew,
                         float* __restrict__ out)
{
    __shared__ float2 XY[512];
    const int tid    = threadIdx.x;
    const int batch  = blockIdx.x >> 5;
    const int seg    = blockIdx.x & 31;
    const int gpbase = (batch << 14) + (seg << 9);

    XY[tid]       = ((const float2*)xnew)[gpbase + tid];
    XY[tid + 256] = ((const float2*)xnew)[gpbase + tid + 256];
    __syncthreads();

    const int lane = tid & 63;
    const int wv   = tid >> 6;
    const int quad = lane >> 4;
    const int lrow = lane & 15;

    // ---- hoist F^T fragments once per wave, straight from global (L2) ----
    const _Float16* Fr = Frt + (batch << 12);
    const _Float16* Fi = Fit + (batch << 12);
    f16x8 Ar[4][2], Ai[4][2];
#pragma unroll
    for (int nt = 0; nt < 4; ++nt)
#pragma unroll
        for (int kt = 0; kt < 2; ++kt) {
            const int off = (((nt << 4) + lrow) << 6) + (kt << 5) + (quad << 3);
            Ar[nt][kt] = *(const f16x8*)(Fr + off);
            Ai[nt][kt] = *(const f16x8*)(Fi + off);
        }

#pragma unroll 1
    for (int mt = 0; mt < 8; ++mt) {
        const int mtbase = (wv << 7) + (mt << 4);
        const float2 xv = XY[mtbase + lrow];

        const float cs1 = cos1_hw(xv.x);   // rotation step e^{2pi i x1}
        const float sn1 = sin1_hw(xv.x);

        f32x4 Gr[4], Gi[4];
#pragma unroll
        for (int nt = 0; nt < 4; ++nt) {
            Gr[nt] = (f32x4){0.f, 0.f, 0.f, 0.f};
            Gi[nt] = (f32x4){0.f, 0.f, 0.f, 0.f};
        }

#pragma unroll
        for (int kt = 0; kt < 2; ++kt) {
            // base frequency of this lane's 8-k run (never crosses k=32)
            const float fb = (float)((quad << 3) - (kt ? 32 : 0));
            float th = xv.x * fb;
            th -= floorf(th);                      // revolutions in [0,1)
            float er = cos1_hw(th);
            float ei = sin1_hw(th);

            F16x8u ur, ui, un;                     // E1r, E1i, -E1i
#pragma unroll
            for (int jp = 0; jp < 4; ++jp) {
                const float er0 = er, ei0 = ei;
                const float er1 = fmaf(-ei0, sn1, er0 * cs1);
                const float ei1 = fmaf( er0, sn1, ei0 * cs1);
                ur.h[jp] = pkrtz(er0, er1);
                ui.h[jp] = pkrtz(ei0, ei1);
                un.h[jp] = pkrtz(-ei0, -ei1);
                if (jp < 3) {
                    er = fmaf(-ei1, sn1, er1 * cs1);
                    ei = fmaf( er1, sn1, ei1 * cs1);
                }
            }
#pragma unroll
            for (int nt = 0; nt < 4; ++nt) {
                Gr[nt] = __builtin_amdgcn_mfma_f32_16x16x32_f16(Ar[nt][kt], ur.v, Gr[nt], 0, 0, 0);
                Gr[nt] = __builtin_amdgcn_mfma_f32_16x16x32_f16(Ai[nt][kt], un.v, Gr[nt], 0, 0, 0);
                Gi[nt] = __builtin_amdgcn_mfma_f32_16x16x32_f16(Ar[nt][kt], ui.v, Gi[nt], 0, 0, 0);
                Gi[nt] = __builtin_amdgcn_mfma_f32_16x16x32_f16(Ai[nt][kt], ur.v, Gi[nt], 0, 0, 0);
            }
        }

        // ---- stage B: red = Re sum_m G[p,m] e^{2pi i x2 f(m)} ----
        const float cs2 = cos1_hw(xv.y);
        const float sn2 = sin1_hw(xv.y);
        float red = 0.0f;
#pragma unroll
        for (int nt = 0; nt < 4; ++nt) {
            // 4-m run never crosses m=32: nt>=2 -> f = m - 64
            const float fb = (float)((nt << 4) + (quad << 2) - (nt >= 2 ? 64 : 0));
            float th = xv.y * fb;
            th -= floorf(th);
            float er = cos1_hw(th);
            float ei = sin1_hw(th);
#pragma unroll
            for (int reg = 0; reg < 4; ++reg) {
                red = fmaf(Gr[nt][reg],  er, red);
                red = fmaf(Gi[nt][reg], -ei, red);
                if (reg < 3) {
                    const float t2 = fmaf(-ei, sn2, er * cs2);
                    ei = fmaf(er, sn2, ei * cs2);
                    er = t2;
                }
            }
        }
        red += __shfl_xor(red, 16, 64);
        red += __shfl_xor(red, 32, 64);
        if (lane < 16)
            out[gpbase + mtbase + lane] = red * (1.0f / 4096.0f);
    }
}

extern "C" void kernel_launch(void* const* d_in, const int* in_sizes, int n_in,
                              void* d_out, int out_size, void* d_ws, size_t ws_size,
                              hipStream_t stream)
{
    const float* y    = (const float*)d_in[0];   // [32, 64, 64]
    const float* xnew = (const float*)d_in[1];   // [32, 128, 128, 2]
    float* out        = (float*)d_out;           // [32, 128, 128]

    // workspace layout (1 MiB total):
    //   T   : 32*64*64 half2  = 512 KiB
    //   Frt : 32*64*64 f16    = 256 KiB
    //   Fit : 32*64*64 f16    = 256 KiB
    f16x2*    T   = (f16x2*)d_ws;
    _Float16* Frt = (_Float16*)((char*)d_ws + (32 << 14));
    _Float16* Fit = Frt + (32 << 12);

    dft_pass1<<<256, 256, 0, stream>>>(y, T);
    dft_pass2<<<256, 256, 0, stream>>>(T, Frt, Fit);
    fourier_interp_cplx<<<1024, 256, 0, stream>>>(Frt, Fit, xnew, out);
}